// Round 1
// baseline (376.525 us; speedup 1.0000x reference)
//
#include <hip/hip_runtime.h>
#include <hip/hip_bf16.h>

typedef __attribute__((ext_vector_type(8))) short bf16x8;
typedef __attribute__((ext_vector_type(4))) float f32x4;

#if __has_builtin(__builtin_amdgcn_exp2f)
#define EXP2(x) __builtin_amdgcn_exp2f(x)
#else
#define EXP2(x) exp2f(x)
#endif

#define LOG2E 1.44269504088896340736f

__device__ __forceinline__ unsigned short f2bf(float f) {
  unsigned int u = __float_as_uint(f);
  u += 0x7FFFu + ((u >> 16) & 1u);   // RNE
  return (unsigned short)(u >> 16);
}

// ---------------- prep: h fp32 -> bf16 ----------------
__global__ void cvt_h_kernel(const float* __restrict__ src, unsigned short* __restrict__ dst, int n4) {
  int i = blockIdx.x * blockDim.x + threadIdx.x;
  if (i >= n4) return;
  float4 v = reinterpret_cast<const float4*>(src)[i];
  ushort4 o;
  o.x = f2bf(v.x); o.y = f2bf(v.y); o.z = f2bf(v.z); o.w = f2bf(v.w);
  reinterpret_cast<ushort4*>(dst)[i] = o;
}

// ---------------- prep: W [512][512] fp32 -> Wt bf16 [512][512], Wt[o][i]=W[i][o], 3 mats ----------------
__global__ void cvt_wt_kernel(const float* __restrict__ Wq, const float* __restrict__ Wk,
                              const float* __restrict__ Wv, unsigned short* __restrict__ wt) {
  __shared__ float tile[32][33];
  const float* W = blockIdx.z == 0 ? Wq : (blockIdx.z == 1 ? Wk : Wv);
  int o0 = blockIdx.x * 32, i0 = blockIdx.y * 32;
  int c = threadIdx.x & 31, r4 = threadIdx.x >> 5;
  for (int rr = 0; rr < 32; rr += 8)
    tile[rr + r4][c] = W[(i0 + rr + r4) * 512 + o0 + c];
  __syncthreads();
  unsigned short* out = wt + blockIdx.z * 512 * 512;
  for (int rr = 0; rr < 32; rr += 8)
    out[(o0 + rr + r4) * 512 + i0 + c] = f2bf(tile[c][rr + r4]);
}

// ---------------- QKV projection GEMM: C = hb(4096x512) @ Wt^T + bias ----------------
// 128x128 tile, 256 threads (4 waves, 2x2 wave grid, 64x64/wave as 4x4 16x16 frags), BK=32.
// mat 0 -> Q [H][N][64] bf16 ; mat 1 -> K [H][N][64] bf16 ; mat 2 -> V^T [H][64][N] bf16
__global__ __launch_bounds__(256) void qkv_gemm_kernel(
    const unsigned short* __restrict__ hb, const unsigned short* __restrict__ wt,
    const float* __restrict__ bq, const float* __restrict__ bk, const float* __restrict__ bv,
    unsigned short* __restrict__ qb, unsigned short* __restrict__ kb, unsigned short* __restrict__ vtb) {
  __shared__ unsigned short Asm[128 * 32];
  __shared__ unsigned short Bsm[128 * 32];
  const int mat = blockIdx.z;
  const unsigned short* Wm = wt + mat * 512 * 512;
  const float* bias = mat == 0 ? bq : (mat == 1 ? bk : bv);
  const int bm = blockIdx.y, bn = blockIdx.x;
  const int t = threadIdx.x;
  const int wid = t >> 6, lane = t & 63;
  const int wr = wid >> 1, wc = wid & 1;
  const int lg = lane >> 4, lr = lane & 15;

  f32x4 acc[4][4];
  for (int a = 0; a < 4; ++a)
    for (int b = 0; b < 4; ++b) acc[a][b] = {0.f, 0.f, 0.f, 0.f};

  for (int kk = 0; kk < 512; kk += 32) {
    __syncthreads();
    for (int u = 0; u < 2; ++u) {
      int idx = t + u * 256;
      int row = idx >> 2, seg = idx & 3;
      *reinterpret_cast<int4*>(&Asm[row * 32 + seg * 8]) =
          *reinterpret_cast<const int4*>(&hb[(bm * 128 + row) * 512 + kk + seg * 8]);
      *reinterpret_cast<int4*>(&Bsm[row * 32 + seg * 8]) =
          *reinterpret_cast<const int4*>(&Wm[(bn * 128 + row) * 512 + kk + seg * 8]);
    }
    __syncthreads();
    bf16x8 a[4], b[4];
    for (int f = 0; f < 4; ++f) {
      a[f] = *reinterpret_cast<const bf16x8*>(&Asm[(wr * 64 + f * 16 + lr) * 32 + lg * 8]);
      b[f] = *reinterpret_cast<const bf16x8*>(&Bsm[(wc * 64 + f * 16 + lr) * 32 + lg * 8]);
    }
    for (int fm = 0; fm < 4; ++fm)
      for (int fn = 0; fn < 4; ++fn)
        acc[fm][fn] = __builtin_amdgcn_mfma_f32_16x16x32_bf16(a[fm], b[fn], acc[fm][fn], 0, 0, 0);
  }

  for (int fm = 0; fm < 4; ++fm)
    for (int fn = 0; fn < 4; ++fn) {
      const int col = bn * 128 + wc * 64 + fn * 16 + lr;
      const float bval = bias[col];
      const int head = col >> 6, dh = col & 63;
      for (int r = 0; r < 4; ++r) {
        const int row = bm * 128 + wr * 64 + fm * 16 + lg * 4 + r;
        const unsigned short bf = f2bf(acc[fm][fn][r] + bval);
        if (mat == 0)      qb[(head * 4096 + row) * 64 + dh] = bf;
        else if (mat == 1) kb[(head * 4096 + row) * 64 + dh] = bf;
        else               vtb[(head * 64 + dh) * 4096 + row] = bf;
      }
    }
}

// ---------------- fused graph attention ----------------
// grid = 128 blocks (i-tile = 32 rows), 512 threads = 8 waves, wave w = head w.
__global__ __launch_bounds__(512) void attn_kernel(
    const unsigned short* __restrict__ qb, const unsigned short* __restrict__ kb,
    const unsigned short* __restrict__ vtb, const float* __restrict__ adj,
    const float* __restrict__ mask, float* __restrict__ out) {
  __shared__ float adj_s[32][36];
  __shared__ float msk_s[32][36];
  __shared__ unsigned short p_s[8][32][40];
  const int t = threadIdx.x;
  const int h = t >> 6, lane = t & 63;
  const int lg = lane >> 4, lr = lane & 15;
  const int i0 = blockIdx.x * 32;
  const unsigned short* Qh = qb + h * 4096 * 64;
  const unsigned short* Kh = kb + h * 4096 * 64;
  const unsigned short* Vh = vtb + h * 64 * 4096;

  // Q fragments (B-operand of swapped QK^T), hoisted for the whole j loop
  bf16x8 qf[2][2];
  for (int in_ = 0; in_ < 2; ++in_)
    for (int ks = 0; ks < 2; ++ks)
      qf[in_][ks] = *reinterpret_cast<const bf16x8*>(&Qh[(i0 + in_ * 16 + lr) * 64 + ks * 32 + lg * 8]);

  f32x4 acc[2][4];
  for (int fi = 0; fi < 2; ++fi)
    for (int fd = 0; fd < 4; ++fd) acc[fi][fd] = {0.f, 0.f, 0.f, 0.f};
  float m[2] = {-1e30f, -1e30f};
  float l[2] = {0.f, 0.f};

  for (int jt = 0; jt < 128; ++jt) {
    const int j0 = jt * 32;
    {  // stage adj (waves 0-3) and mask (waves 4-7) tiles: 32x32 fp32 each
      const int tt = t & 255;
      const int row = tt >> 3, c4 = (tt & 7) * 4;
      const float4 v = *reinterpret_cast<const float4*>(
          (t < 256 ? adj : mask) + (size_t)(i0 + row) * 4096 + j0 + c4);
      float* dstp = (t < 256) ? &adj_s[row][c4] : &msk_s[row][c4];
      *reinterpret_cast<float4*>(dstp) = v;
    }
    __syncthreads();

    // S^T = K_tile(32xj,64d) @ Q_tile^T  -> D[row=j-local][col=i-local]
    f32x4 s[2][2];
    for (int jm = 0; jm < 2; ++jm)
      for (int in_ = 0; in_ < 2; ++in_) s[jm][in_] = {0.f, 0.f, 0.f, 0.f};
    for (int jm = 0; jm < 2; ++jm)
      for (int ks = 0; ks < 2; ++ks) {
        const bf16x8 kf = *reinterpret_cast<const bf16x8*>(&Kh[(j0 + jm * 16 + lr) * 64 + ks * 32 + lg * 8]);
        for (int in_ = 0; in_ < 2; ++in_)
          s[jm][in_] = __builtin_amdgcn_mfma_f32_16x16x32_bf16(kf, qf[in_][ks], s[jm][in_], 0, 0, 0);
      }

    // score = (adj*qk + mask) * (scale*log2e); per-lane rows are i = in_*16+lr
    float sc[2][2][4];
    float tm[2] = {-1e30f, -1e30f};
    for (int in_ = 0; in_ < 2; ++in_)
      for (int jm = 0; jm < 2; ++jm) {
        const float4 av = *reinterpret_cast<const float4*>(&adj_s[in_ * 16 + lr][jm * 16 + lg * 4]);
        const float4 mv = *reinterpret_cast<const float4*>(&msk_s[in_ * 16 + lr][jm * 16 + lg * 4]);
        const float a0[4] = {av.x, av.y, av.z, av.w};
        const float m0[4] = {mv.x, mv.y, mv.z, mv.w};
        for (int r = 0; r < 4; ++r) {
          const float v = (a0[r] * s[jm][in_][r] + m0[r]) * (0.125f * LOG2E);
          sc[in_][jm][r] = v;
          tm[in_] = fmaxf(tm[in_], v);
        }
      }
    for (int in_ = 0; in_ < 2; ++in_) {
      tm[in_] = fmaxf(tm[in_], __shfl_xor(tm[in_], 16));
      tm[in_] = fmaxf(tm[in_], __shfl_xor(tm[in_], 32));
    }
    const float mn0 = fmaxf(m[0], tm[0]);
    const float mn1 = fmaxf(m[1], tm[1]);
    if (__any(tm[0] > m[0] || tm[1] > m[1])) {  // rescale accumulators (skipped when max unchanged)
      const float f0 = EXP2(m[0] - mn0);
      const float f1 = EXP2(m[1] - mn1);
      l[0] *= f0; l[1] *= f1;
      m[0] = mn0; m[1] = mn1;
      const float ff[2] = {f0, f1};
      for (int fi = 0; fi < 2; ++fi)
        for (int r = 0; r < 4; ++r) {
          const float fr = __int_as_float(
              __builtin_amdgcn_ds_bpermute((lg * 4 + r) << 2, __float_as_int(ff[fi])));
          for (int fd = 0; fd < 4; ++fd) acc[fi][fd][r] *= fr;
        }
    }

    // p = exp2(sc - m), row sums, and P -> per-wave LDS buffer as P[i][j] bf16
    float ts[2] = {0.f, 0.f};
    for (int in_ = 0; in_ < 2; ++in_)
      for (int jm = 0; jm < 2; ++jm) {
        ushort4 w;
        unsigned short* wp = reinterpret_cast<unsigned short*>(&w);
        for (int r = 0; r < 4; ++r) {
          const float p = EXP2(sc[in_][jm][r] - m[in_]);
          ts[in_] += p;
          wp[r] = f2bf(p);
        }
        *reinterpret_cast<ushort4*>(&p_s[h][in_ * 16 + lr][jm * 16 + lg * 4]) = w;
      }
    for (int in_ = 0; in_ < 2; ++in_) {
      ts[in_] += __shfl_xor(ts[in_], 16);
      ts[in_] += __shfl_xor(ts[in_], 32);
      l[in_] += ts[in_];
    }

    // PV: out(32xi,64dh) += P(32x32) @ V(32x64); A-frag from p_s, B-frag from V^T rows
    bf16x8 pa[2];
    for (int fi = 0; fi < 2; ++fi)
      pa[fi] = *reinterpret_cast<const bf16x8*>(&p_s[h][fi * 16 + lr][lg * 8]);
    for (int fd = 0; fd < 4; ++fd) {
      const bf16x8 vf = *reinterpret_cast<const bf16x8*>(&Vh[(size_t)(fd * 16 + lr) * 4096 + j0 + lg * 8]);
      for (int fi = 0; fi < 2; ++fi)
        acc[fi][fd] = __builtin_amdgcn_mfma_f32_16x16x32_bf16(pa[fi], vf, acc[fi][fd], 0, 0, 0);
    }
    __syncthreads();
  }

  // epilogue: out = acc / l  (redistribute l to accumulator row layout)
  for (int fi = 0; fi < 2; ++fi)
    for (int r = 0; r < 4; ++r) {
      const float lrw = __int_as_float(
          __builtin_amdgcn_ds_bpermute((lg * 4 + r) << 2, __float_as_int(l[fi])));
      const float inv = 1.0f / lrw;
      const int row = i0 + fi * 16 + lg * 4 + r;
      for (int fd = 0; fd < 4; ++fd)
        out[(size_t)row * 512 + h * 64 + fd * 16 + lr] = acc[fi][fd][r] * inv;
    }
}

extern "C" void kernel_launch(void* const* d_in, const int* in_sizes, int n_in,
                              void* d_out, int out_size, void* d_ws, size_t ws_size,
                              hipStream_t stream) {
  const float* h    = (const float*)d_in[0];
  const float* adj  = (const float*)d_in[1];
  const float* mask = (const float*)d_in[2];
  const float* Wq   = (const float*)d_in[3];
  const float* bq   = (const float*)d_in[4];
  const float* Wk   = (const float*)d_in[5];
  const float* bk   = (const float*)d_in[6];
  const float* Wv   = (const float*)d_in[7];
  const float* bv   = (const float*)d_in[8];
  float* out = (float*)d_out;

  char* ws = (char*)d_ws;
  unsigned short* hb = (unsigned short*)(ws);                    // 4 MiB   (4096x512 bf16)
  unsigned short* wt = (unsigned short*)(ws + (4u  << 20));      // 1.5 MiB (3x512x512 bf16)
  unsigned short* qb = (unsigned short*)(ws + (6u  << 20));      // 4 MiB   [H][N][64]
  unsigned short* kb = (unsigned short*)(ws + (10u << 20));      // 4 MiB   [H][N][64]
  unsigned short* vt = (unsigned short*)(ws + (14u << 20));      // 4 MiB   [H][64][N]

  cvt_h_kernel<<<dim3(2048), dim3(256), 0, stream>>>(h, hb, 4096 * 512 / 4);
  cvt_wt_kernel<<<dim3(16, 16, 3), dim3(256), 0, stream>>>(Wq, Wk, Wv, wt);
  qkv_gemm_kernel<<<dim3(4, 32, 3), dim3(256), 0, stream>>>(hb, wt, bq, bk, bv, qb, kb, vt);
  attn_kernel<<<dim3(128), dim3(512), 0, stream>>>(qb, kb, vt, adj, mask, out);
}

// Round 2
// 178.368 us; speedup vs baseline: 2.1109x; 2.1109x over previous
//
#include <hip/hip_runtime.h>
#include <hip/hip_bf16.h>

typedef __attribute__((ext_vector_type(8))) short bf16x8;
typedef __attribute__((ext_vector_type(4))) float f32x4;

#define LOG2E 1.44269504088896340736f
#define NSPLIT 4
#define NT_PER 32   // j-tiles of 32 per split (128 total)

__device__ __forceinline__ unsigned short f2bf(float f) {
  unsigned int u = __float_as_uint(f);
  u += 0x7FFFu + ((u >> 16) & 1u);   // RNE
  return (unsigned short)(u >> 16);
}

// ---------------- prep: h fp32 -> bf16 ----------------
__global__ void cvt_h_kernel(const float* __restrict__ src, unsigned short* __restrict__ dst, int n4) {
  int i = blockIdx.x * blockDim.x + threadIdx.x;
  if (i >= n4) return;
  float4 v = reinterpret_cast<const float4*>(src)[i];
  ushort4 o;
  o.x = f2bf(v.x); o.y = f2bf(v.y); o.z = f2bf(v.z); o.w = f2bf(v.w);
  reinterpret_cast<ushort4*>(dst)[i] = o;
}

// ---------------- prep: W [512][512] fp32 -> Wt bf16, Wt[o][i]=W[i][o], 3 mats ----------------
__global__ void cvt_wt_kernel(const float* __restrict__ Wq, const float* __restrict__ Wk,
                              const float* __restrict__ Wv, unsigned short* __restrict__ wt) {
  __shared__ float tile[32][33];
  const float* W = blockIdx.z == 0 ? Wq : (blockIdx.z == 1 ? Wk : Wv);
  int o0 = blockIdx.x * 32, i0 = blockIdx.y * 32;
  int c = threadIdx.x & 31, r4 = threadIdx.x >> 5;
  for (int rr = 0; rr < 32; rr += 8)
    tile[rr + r4][c] = W[(i0 + rr + r4) * 512 + o0 + c];
  __syncthreads();
  unsigned short* out = wt + blockIdx.z * 512 * 512;
  for (int rr = 0; rr < 32; rr += 8)
    out[(o0 + rr + r4) * 512 + i0 + c] = f2bf(tile[c][rr + r4]);
}

// ---------------- QKV projection GEMM: C = hb(4096x512) @ Wt^T + bias ----------------
__global__ __launch_bounds__(256) void qkv_gemm_kernel(
    const unsigned short* __restrict__ hb, const unsigned short* __restrict__ wt,
    const float* __restrict__ bq, const float* __restrict__ bk, const float* __restrict__ bv,
    unsigned short* __restrict__ qb, unsigned short* __restrict__ kb, unsigned short* __restrict__ vtb) {
  __shared__ unsigned short Asm[128 * 32];
  __shared__ unsigned short Bsm[128 * 32];
  const int mat = blockIdx.z;
  const unsigned short* Wm = wt + mat * 512 * 512;
  const float* bias = mat == 0 ? bq : (mat == 1 ? bk : bv);
  const int bm = blockIdx.y, bn = blockIdx.x;
  const int t = threadIdx.x;
  const int wid = t >> 6, lane = t & 63;
  const int wr = wid >> 1, wc = wid & 1;
  const int lg = lane >> 4, lr = lane & 15;

  f32x4 acc[4][4];
  for (int a = 0; a < 4; ++a)
    for (int b = 0; b < 4; ++b) acc[a][b] = {0.f, 0.f, 0.f, 0.f};

  for (int kk = 0; kk < 512; kk += 32) {
    __syncthreads();
    for (int u = 0; u < 2; ++u) {
      int idx = t + u * 256;
      int row = idx >> 2, seg = idx & 3;
      *reinterpret_cast<int4*>(&Asm[row * 32 + seg * 8]) =
          *reinterpret_cast<const int4*>(&hb[(bm * 128 + row) * 512 + kk + seg * 8]);
      *reinterpret_cast<int4*>(&Bsm[row * 32 + seg * 8]) =
          *reinterpret_cast<const int4*>(&Wm[(bn * 128 + row) * 512 + kk + seg * 8]);
    }
    __syncthreads();
    bf16x8 a[4], b[4];
    for (int f = 0; f < 4; ++f) {
      a[f] = *reinterpret_cast<const bf16x8*>(&Asm[(wr * 64 + f * 16 + lr) * 32 + lg * 8]);
      b[f] = *reinterpret_cast<const bf16x8*>(&Bsm[(wc * 64 + f * 16 + lr) * 32 + lg * 8]);
    }
    for (int fm = 0; fm < 4; ++fm)
      for (int fn = 0; fn < 4; ++fn)
        acc[fm][fn] = __builtin_amdgcn_mfma_f32_16x16x32_bf16(a[fm], b[fn], acc[fm][fn], 0, 0, 0);
  }

  for (int fm = 0; fm < 4; ++fm)
    for (int fn = 0; fn < 4; ++fn) {
      const int col = bn * 128 + wc * 64 + fn * 16 + lr;
      const float bval = bias[col];
      const int head = col >> 6, dh = col & 63;
      for (int r = 0; r < 4; ++r) {
        const int row = bm * 128 + wr * 64 + fm * 16 + lg * 4 + r;
        const unsigned short bf = f2bf(acc[fm][fn][r] + bval);
        if (mat == 0)      qb[(head * 4096 + row) * 64 + dh] = bf;
        else if (mat == 1) kb[(head * 4096 + row) * 64 + dh] = bf;
        else               vtb[(head * 64 + dh) * 4096 + row] = bf;
      }
    }
}

// ---------------- fused graph attention, split-j partials ----------------
// grid = (128 i-tiles, NSPLIT j-segments), 512 threads = 8 waves, wave = head.
// Writes UNNORMALIZED acc partials + per-row (m,l) to workspace.
__global__ __launch_bounds__(512) void attn_kernel(
    const unsigned short* __restrict__ qb, const unsigned short* __restrict__ kb,
    const unsigned short* __restrict__ vtb, const float* __restrict__ adj,
    const float* __restrict__ mask, float* __restrict__ pacc, float* __restrict__ pml) {
  __shared__ float adj_s[2][32][36];
  __shared__ float msk_s[2][32][36];
  __shared__ unsigned short p_s[8][32][40];
  const int t = threadIdx.x;
  const int h = t >> 6, lane = t & 63;
  const int lg = lane >> 4, lr = lane & 15;
  const int i0 = blockIdx.x * 32;
  const int sp = blockIdx.y;
  const unsigned short* Qh = qb + h * 4096 * 64;
  const unsigned short* Kh = kb + h * 4096 * 64;
  const unsigned short* Vh = vtb + h * 64 * 4096;

  // staging indices (all 512 threads): t<256 -> adj tile, else mask tile
  const int tt = t & 255;
  const int srow = tt >> 3, sc4 = (tt & 7) * 4;
  const float* sbase = (t < 256 ? adj : mask) + (size_t)(i0 + srow) * 4096 + sc4;

  // Q fragments hoisted (B-operand of swapped QK^T)
  bf16x8 qf[2][2];
  for (int in_ = 0; in_ < 2; ++in_)
    for (int ks = 0; ks < 2; ++ks)
      qf[in_][ks] = *reinterpret_cast<const bf16x8*>(&Qh[(i0 + in_ * 16 + lr) * 64 + ks * 32 + lg * 8]);

  f32x4 acc[2][4];
  for (int fi = 0; fi < 2; ++fi)
    for (int fd = 0; fd < 4; ++fd) acc[fi][fd] = {0.f, 0.f, 0.f, 0.f};
  float m[2] = {-1e30f, -1e30f};
  float l[2] = {0.f, 0.f};

  // prologue: stage first tile of this split
  {
    const int j0 = sp * NT_PER * 32;
    const float4 v = *reinterpret_cast<const float4*>(sbase + j0);
    float* dstp = (t < 256) ? &adj_s[0][srow][sc4] : &msk_s[0][srow][sc4];
    *reinterpret_cast<float4*>(dstp) = v;
  }
  __syncthreads();

  for (int it = 0; it < NT_PER; ++it) {
    const int j0 = (sp * NT_PER + it) * 32;
    const int cur = it & 1;
    // T14: issue next tile's global loads early
    float4 nv;
    const bool havenext = (it + 1 < NT_PER);
    if (havenext) nv = *reinterpret_cast<const float4*>(sbase + j0 + 32);

    // S^T = K_tile @ Q_tile^T
    f32x4 s[2][2];
    for (int jm = 0; jm < 2; ++jm)
      for (int in_ = 0; in_ < 2; ++in_) s[jm][in_] = {0.f, 0.f, 0.f, 0.f};
    for (int jm = 0; jm < 2; ++jm)
      for (int ks = 0; ks < 2; ++ks) {
        const bf16x8 kf = *reinterpret_cast<const bf16x8*>(&Kh[(j0 + jm * 16 + lr) * 64 + ks * 32 + lg * 8]);
        for (int in_ = 0; in_ < 2; ++in_)
          s[jm][in_] = __builtin_amdgcn_mfma_f32_16x16x32_bf16(kf, qf[in_][ks], s[jm][in_], 0, 0, 0);
      }

    // score = (adj*qk + mask) * (scale*log2e)
    float sc[2][2][4];
    float tm[2] = {-1e30f, -1e30f};
    for (int in_ = 0; in_ < 2; ++in_)
      for (int jm = 0; jm < 2; ++jm) {
        const float4 av = *reinterpret_cast<const float4*>(&adj_s[cur][in_ * 16 + lr][jm * 16 + lg * 4]);
        const float4 mv = *reinterpret_cast<const float4*>(&msk_s[cur][in_ * 16 + lr][jm * 16 + lg * 4]);
        const float a0[4] = {av.x, av.y, av.z, av.w};
        const float m0[4] = {mv.x, mv.y, mv.z, mv.w};
        for (int r = 0; r < 4; ++r) {
          const float v = (a0[r] * s[jm][in_][r] + m0[r]) * (0.125f * LOG2E);
          sc[in_][jm][r] = v;
          tm[in_] = fmaxf(tm[in_], v);
        }
      }
    for (int in_ = 0; in_ < 2; ++in_) {
      tm[in_] = fmaxf(tm[in_], __shfl_xor(tm[in_], 16));
      tm[in_] = fmaxf(tm[in_], __shfl_xor(tm[in_], 32));
    }
    const float mn0 = fmaxf(m[0], tm[0]);
    const float mn1 = fmaxf(m[1], tm[1]);
    if (__any(tm[0] > m[0] || tm[1] > m[1])) {
      const float f0 = exp2f(m[0] - mn0);
      const float f1 = exp2f(m[1] - mn1);
      l[0] *= f0; l[1] *= f1;
      m[0] = mn0; m[1] = mn1;
      const float ff[2] = {f0, f1};
      for (int fi = 0; fi < 2; ++fi)
        for (int r = 0; r < 4; ++r) {
          const float fr = __int_as_float(
              __builtin_amdgcn_ds_bpermute((lg * 4 + r) << 2, __float_as_int(ff[fi])));
          for (int fd = 0; fd < 4; ++fd) acc[fi][fd][r] *= fr;
        }
    }

    // p = exp2(sc - m) -> per-wave LDS P[i][j] bf16; accumulate row sums
    float ts[2] = {0.f, 0.f};
    for (int in_ = 0; in_ < 2; ++in_)
      for (int jm = 0; jm < 2; ++jm) {
        ushort4 w;
        unsigned short* wp = reinterpret_cast<unsigned short*>(&w);
        for (int r = 0; r < 4; ++r) {
          const float p = exp2f(sc[in_][jm][r] - m[in_]);
          ts[in_] += p;
          wp[r] = f2bf(p);
        }
        *reinterpret_cast<ushort4*>(&p_s[h][in_ * 16 + lr][jm * 16 + lg * 4]) = w;
      }
    for (int in_ = 0; in_ < 2; ++in_) {
      ts[in_] += __shfl_xor(ts[in_], 16);
      ts[in_] += __shfl_xor(ts[in_], 32);
      l[in_] += ts[in_];
    }

    // PV
    bf16x8 pa[2];
    for (int fi = 0; fi < 2; ++fi)
      pa[fi] = *reinterpret_cast<const bf16x8*>(&p_s[h][fi * 16 + lr][lg * 8]);
    for (int fd = 0; fd < 4; ++fd) {
      const bf16x8 vf = *reinterpret_cast<const bf16x8*>(&Vh[(size_t)(fd * 16 + lr) * 4096 + j0 + lg * 8]);
      for (int fi = 0; fi < 2; ++fi)
        acc[fi][fd] = __builtin_amdgcn_mfma_f32_16x16x32_bf16(pa[fi], vf, acc[fi][fd], 0, 0, 0);
    }

    // late LDS write of next tile, single barrier per iteration
    if (havenext) {
      float* dstp = (t < 256) ? &adj_s[cur ^ 1][srow][sc4] : &msk_s[cur ^ 1][srow][sc4];
      *reinterpret_cast<float4*>(dstp) = nv;
    }
    __syncthreads();
  }

  // epilogue: write unnormalized partials + (m,l)
  float* pa_base = pacc + ((size_t)sp * 4096 + i0) * 512;
  for (int fi = 0; fi < 2; ++fi)
    for (int fd = 0; fd < 4; ++fd)
      for (int r = 0; r < 4; ++r) {
        const int rowl = fi * 16 + lg * 4 + r;
        const int col = h * 64 + fd * 16 + lr;
        pa_base[rowl * 512 + col] = acc[fi][fd][r];
      }
  if (lane < 16) {
    for (int in_ = 0; in_ < 2; ++in_) {
      const int row = i0 + in_ * 16 + lane;
      float2 v; v.x = m[in_]; v.y = l[in_];
      reinterpret_cast<float2*>(pml)[((size_t)sp * 8 + h) * 4096 + row] = v;
    }
  }
}

// ---------------- combine splits: out = sum_s acc_s*2^(m_s-M) / sum_s l_s*2^(m_s-M) ----------------
__global__ __launch_bounds__(128) void combine_kernel(
    const float* __restrict__ pacc, const float* __restrict__ pml, float* __restrict__ out) {
  const int row = blockIdx.x;
  const int t = threadIdx.x;
  const int col = t * 4;
  const int head = col >> 6;

  float ms[NSPLIT], ls[NSPLIT];
  float M = -1e30f;
  for (int s = 0; s < NSPLIT; ++s) {
    const float2 v = reinterpret_cast<const float2*>(pml)[((size_t)s * 8 + head) * 4096 + row];
    ms[s] = v.x; ls[s] = v.y;
    M = fmaxf(M, v.x);
  }
  float denom = 0.f;
  float w[NSPLIT];
  for (int s = 0; s < NSPLIT; ++s) {
    w[s] = exp2f(ms[s] - M);
    denom += ls[s] * w[s];
  }
  const float inv = 1.0f / denom;
  float4 o = {0.f, 0.f, 0.f, 0.f};
  for (int s = 0; s < NSPLIT; ++s) {
    const float4 a = *reinterpret_cast<const float4*>(&pacc[((size_t)s * 4096 + row) * 512 + col]);
    o.x += a.x * w[s]; o.y += a.y * w[s]; o.z += a.z * w[s]; o.w += a.w * w[s];
  }
  o.x *= inv; o.y *= inv; o.z *= inv; o.w *= inv;
  *reinterpret_cast<float4*>(&out[(size_t)row * 512 + col]) = o;
}

extern "C" void kernel_launch(void* const* d_in, const int* in_sizes, int n_in,
                              void* d_out, int out_size, void* d_ws, size_t ws_size,
                              hipStream_t stream) {
  const float* h    = (const float*)d_in[0];
  const float* adj  = (const float*)d_in[1];
  const float* mask = (const float*)d_in[2];
  const float* Wq   = (const float*)d_in[3];
  const float* bq   = (const float*)d_in[4];
  const float* Wk   = (const float*)d_in[5];
  const float* bk   = (const float*)d_in[6];
  const float* Wv   = (const float*)d_in[7];
  const float* bv   = (const float*)d_in[8];
  float* out = (float*)d_out;

  char* ws = (char*)d_ws;
  unsigned short* hb = (unsigned short*)(ws);                    // 4 MiB
  unsigned short* wt = (unsigned short*)(ws + (4u  << 20));      // 1.5 MiB
  unsigned short* qb = (unsigned short*)(ws + (6u  << 20));      // 4 MiB [H][N][64]
  unsigned short* kb = (unsigned short*)(ws + (10u << 20));      // 4 MiB [H][N][64]
  unsigned short* vt = (unsigned short*)(ws + (14u << 20));      // 4 MiB [H][64][N]
  float* pacc = (float*)(ws + (20u << 20));                      // 32 MiB [NSPLIT][4096][512]
  float* pml  = (float*)(ws + (52u << 20));                      // 1 MiB  [NSPLIT][8][4096] float2

  cvt_h_kernel<<<dim3(2048), dim3(256), 0, stream>>>(h, hb, 4096 * 512 / 4);
  cvt_wt_kernel<<<dim3(16, 16, 3), dim3(256), 0, stream>>>(Wq, Wk, Wv, wt);
  qkv_gemm_kernel<<<dim3(4, 32, 3), dim3(256), 0, stream>>>(hb, wt, bq, bk, bv, qb, kb, vt);
  attn_kernel<<<dim3(128, NSPLIT), dim3(512), 0, stream>>>(qb, kb, vt, adj, mask, pacc, pml);
  combine_kernel<<<dim3(4096), dim3(128), 0, stream>>>(pacc, pml, out);
}